// Round 2
// baseline (127.968 us; speedup 1.0000x reference)
//
#include <hip/hip_runtime.h>

// KVCache scatter-update, MI355X.
// Constants: N_KV_HEADS=8, MAX_CONTEXT=8192, HEAD_DIM=128, N_NEW=16, fp32.
// out = concat(kout, vout), each (1,8,8192,128) fp32 = 33.55 MB.
//
// Strategy: bulk clone via two D2D blits (copy engine at BW ceiling),
// then a tiny scatter kernel overwriting 16 rows/head/tensor (512 KB).
// Stream order guarantees scatter lands after the clone.

#define NNEW 16
#define NH   8
#define CTX  8192
#define HD4  32   // HEAD_DIM / 4 floats per float4

__global__ __launch_bounds__(256) void kv_scatter_kernel(
    const int* __restrict__ pos,
    const float4* __restrict__ knew,
    const float4* __restrict__ vnew,
    float4* __restrict__ out)
{
    const unsigned i = blockIdx.x * 256u + threadIdx.x;  // [0, 8192)
    const unsigned is_v = i >> 12;        // 0 = k, 1 = v
    const unsigned j    = i & 4095u;      // index within (8,16,32) new tensor
    const unsigned h    = j >> 9;         // head
    const int      n    = (int)((j >> 5) & 15u);  // new-row index
    const unsigned d4   = j & 31u;        // float4 within head_dim

    // pos: wave-uniform scalar loads. Last-wins for duplicate positions
    // (numpy sequential-assignment semantics): if any later row targets the
    // same position, this row's write is suppressed.
    const int s = pos[n];
    bool shadowed = false;
#pragma unroll
    for (int m = 0; m < NNEW; ++m) {
        shadowed |= (m > n) & (pos[m] == s);
    }
    if (shadowed) return;

    const float4* __restrict__ src = is_v ? vnew : knew;
    const float4 val = src[j];  // new tensors are contiguous (8,16,32) float4

    const unsigned dst = is_v * (NH * CTX * HD4)
                       + (h * CTX + (unsigned)s) * HD4 + d4;
    out[dst] = val;
}

extern "C" void kernel_launch(void* const* d_in, const int* in_sizes, int n_in,
                              void* d_out, int out_size, void* d_ws, size_t ws_size,
                              hipStream_t stream) {
    // setup_inputs order: pos_ids, k, v, k_cache, v_cache
    const int*    pos    = (const int*)   d_in[0];
    const float4* knew   = (const float4*)d_in[1];
    const float4* vnew   = (const float4*)d_in[2];
    const void*   kcache = d_in[3];
    const void*   vcache = d_in[4];

    const size_t cache_bytes = (size_t)NH * CTX * 128 * sizeof(float);  // 33554432

    // Bulk clone at copy-engine bandwidth.
    hipMemcpyAsync(d_out, kcache, cache_bytes, hipMemcpyDeviceToDevice, stream);
    hipMemcpyAsync((char*)d_out + cache_bytes, vcache, cache_bytes,
                   hipMemcpyDeviceToDevice, stream);

    // Scatter the 16 new rows per head per tensor: 2*8*16*32 = 8192 float4s.
    kv_scatter_kernel<<<8192 / 256, 256, 0, stream>>>(
        pos, knew, vnew, (float4*)d_out);
}

// Round 4
// 124.663 us; speedup vs baseline: 1.0265x; 1.0265x over previous
//
#include <hip/hip_runtime.h>

// KVCache scatter-update, MI355X (gfx950).
// Constants: N_KV_HEADS=8, MAX_CONTEXT=8192, HEAD_DIM=128, N_NEW=16, fp32.
// out = concat(kout, vout) flat, each (1,8,8192,128) fp32 (33.55 MB).
//
// Fused clone+scatter in ONE kernel (measured best structure, round 1:
// 119 µs total vs 128 µs for memcpy+scatter — SDMA blits lose).
// This round:
//  - block-uniform scatter test: a 256-thread block covers 8 consecutive
//    seq rows of one head; skip the per-thread 16-compare match loop
//    unless one of pos[] falls in the block's row window (~99.6% of blocks
//    take the pure-copy fast path, no divergence on the load).
//  - non-temporal loads/stores (zero reuse, skip L2 allocation) via native
//    clang vector type (HIP_vector_type struct is rejected by the builtin).
//
// Traffic floor: 67 MB read + 67 MB write = 134 MB @ ~6.5 TB/s ≈ 21 µs.

#define NNEW 16
#define NH   8
#define CTX  8192
#define HD4  32   // HEAD_DIM / 4 = float4s per row

typedef float v4f __attribute__((ext_vector_type(4)));

__global__ __launch_bounds__(256) void kv_fused_kernel(
    const int* __restrict__ pos,
    const v4f* __restrict__ knew,
    const v4f* __restrict__ vnew,
    const v4f* __restrict__ kcache,
    const v4f* __restrict__ vcache,
    v4f* __restrict__ out)
{
    const unsigned i    = blockIdx.x * 256u + threadIdx.x;   // [0, 2^22)
    const unsigned is_v = i >> 21;
    const unsigned j    = i & ((1u << 21) - 1u);   // index within one cache
    const v4f* __restrict__ csrc = is_v ? vcache : kcache;

    // Unconditional streaming read of the cache line (nt: no L2 reuse).
    v4f val = __builtin_nontemporal_load(&csrc[j]);

    // Block-uniform window test: this block's 8 seq rows are
    // [s0, s0+8) within one head (1024 blocks per head, no straddle).
    const unsigned s0 = ((blockIdx.x * 256u) >> 5) & (CTX - 1u);
    bool block_hit = false;
#pragma unroll
    for (int n = 0; n < NNEW; ++n) {
        block_hit |= ((unsigned)(pos[n] - (int)s0) < 8u);  // uniform s_loads
    }

    if (block_hit) {   // rare (~16/1024 blocks per head), wave-uniform branch
        const int      s  = (int)((j >> 5) & (CTX - 1u));
        const unsigned h  = j >> 18;
        const unsigned d4 = j & (HD4 - 1u);
        // Last match wins => numpy sequential-assignment semantics for dups.
        int match = -1;
#pragma unroll
        for (int n = 0; n < NNEW; ++n) {
            if (pos[n] == s) match = n;
        }
        if (match >= 0) {
            const v4f* __restrict__ nsrc = is_v ? vnew : knew;
            val = nsrc[(unsigned)(h * NNEW + match) * HD4 + d4];
        }
    }

    __builtin_nontemporal_store(val, &out[i]);
}

extern "C" void kernel_launch(void* const* d_in, const int* in_sizes, int n_in,
                              void* d_out, int out_size, void* d_ws, size_t ws_size,
                              hipStream_t stream) {
    // setup_inputs order: pos_ids, k, v, k_cache, v_cache
    const int* pos    = (const int*)d_in[0];
    const v4f* knew   = (const v4f*)d_in[1];
    const v4f* vnew   = (const v4f*)d_in[2];
    const v4f* kcache = (const v4f*)d_in[3];
    const v4f* vcache = (const v4f*)d_in[4];

    // 2 caches * 2^21 float4s, 256 threads/block -> 16384 blocks
    kv_fused_kernel<<<(1u << 22) / 256u, 256, 0, stream>>>(
        pos, knew, vnew, kcache, vcache, (v4f*)d_out);
}

// Round 5
// 119.658 us; speedup vs baseline: 1.0694x; 1.0418x over previous
//
#include <hip/hip_runtime.h>

// KVCache scatter-update, MI355X (gfx950).
// Constants: N_KV_HEADS=8, MAX_CONTEXT=8192, HEAD_DIM=128, N_NEW=16, fp32.
// out = concat(kout, vout) flat, each (1,8,8192,128) fp32 (33.55 MB).
//
// Measured history:
//   R1 fused plain float4 copy+scatter ............ 119.1 µs  (best)
//   R2 hipMemcpyAsync x2 + scatter kernel ......... 128.0 µs  (SDMA loses)
//   R4 fused + nontemporal + block-uniform test ... 124.7 µs  (nt regressed)
// This round: R1 structure + block-uniform fast path, NO nontemporal.
// Our dispatch never appears in rocprof top-5 (<41 µs vs ~21 µs traffic
// floor = 134 MB @ 6.4 TB/s); remaining ~95-100 µs of dur_us is fixed
// harness restore/poison work.

#define NNEW 16
#define NH   8
#define CTX  8192
#define HD4  32   // HEAD_DIM / 4 = float4s per row

__global__ __launch_bounds__(256) void kv_fused_kernel(
    const int* __restrict__ pos,
    const float4* __restrict__ knew,
    const float4* __restrict__ vnew,
    const float4* __restrict__ kcache,
    const float4* __restrict__ vcache,
    float4* __restrict__ out)
{
    const unsigned i    = blockIdx.x * 256u + threadIdx.x;   // [0, 2^22)
    const unsigned is_v = i >> 21;
    const unsigned j    = i & ((1u << 21) - 1u);   // index within one cache
    const float4* __restrict__ csrc = is_v ? vcache : kcache;

    // Unconditional streaming read of the cache line.
    float4 val = csrc[j];

    // Block-uniform window test: this block's 8 seq rows are
    // [s0, s0+8) within one head (1024 blocks per head, no straddle).
    const unsigned s0 = ((blockIdx.x * 256u) >> 5) & (CTX - 1u);
    bool block_hit = false;
#pragma unroll
    for (int n = 0; n < NNEW; ++n) {
        block_hit |= ((unsigned)(pos[n] - (int)s0) < 8u);  // uniform s_loads
    }

    if (block_hit) {   // rare (~16/1024 blocks per head), wave-uniform branch
        const int      s  = (int)((j >> 5) & (CTX - 1u));
        const unsigned h  = j >> 18;
        const unsigned d4 = j & (HD4 - 1u);
        // Last match wins => numpy sequential-assignment semantics for dups.
        int match = -1;
#pragma unroll
        for (int n = 0; n < NNEW; ++n) {
            if (pos[n] == s) match = n;
        }
        if (match >= 0) {
            const float4* __restrict__ nsrc = is_v ? vnew : knew;
            val = nsrc[(unsigned)(h * NNEW + match) * HD4 + d4];
        }
    }

    out[i] = val;
}

extern "C" void kernel_launch(void* const* d_in, const int* in_sizes, int n_in,
                              void* d_out, int out_size, void* d_ws, size_t ws_size,
                              hipStream_t stream) {
    // setup_inputs order: pos_ids, k, v, k_cache, v_cache
    const int*    pos    = (const int*)   d_in[0];
    const float4* knew   = (const float4*)d_in[1];
    const float4* vnew   = (const float4*)d_in[2];
    const float4* kcache = (const float4*)d_in[3];
    const float4* vcache = (const float4*)d_in[4];

    // 2 caches * 2^21 float4s, 256 threads/block -> 16384 blocks
    kv_fused_kernel<<<(1u << 22) / 256u, 256, 0, stream>>>(
        pos, knew, vnew, kcache, vcache, (float4*)d_out);
}